// Round 15
// baseline (4577.370 us; speedup 1.0000x reference)
//
#include <hip/hip_runtime.h>

typedef __bf16 bf16x8 __attribute__((ext_vector_type(8)));
typedef float f32x4 __attribute__((ext_vector_type(4)));
typedef unsigned long long u64;

__device__ inline float sigm(float x) { return 1.0f / (1.0f + __expf(-x)); }
__device__ inline float tanh_f(float x) {
    float e = __expf(2.0f * x);
    return 1.0f - 2.0f / (e + 1.0f);
}

__device__ inline unsigned short f2bf(float f) {
    __bf16 h = (__bf16)f;
    return __builtin_bit_cast(unsigned short, h);
}

__device__ inline bf16x8 cvt8(float4 lo, float4 hi) {
    bf16x8 r;
    r[0] = (__bf16)lo.x; r[1] = (__bf16)lo.y; r[2] = (__bf16)lo.z; r[3] = (__bf16)lo.w;
    r[4] = (__bf16)hi.x; r[5] = (__bf16)hi.y; r[6] = (__bf16)hi.z; r[7] = (__bf16)hi.w;
    return r;
}

// compiler-visible LLC-coherent ops (sc0 sc1, no fences, counted vmcnt)
__device__ inline u64 ld64c(const u64* p) {
    return __hip_atomic_load(p, __ATOMIC_RELAXED, __HIP_MEMORY_SCOPE_AGENT);
}
__device__ inline void st32c(unsigned int* p, unsigned int v) {
    __hip_atomic_store(p, v, __ATOMIC_RELAXED, __HIP_MEMORY_SCOPE_AGENT);
}

// ---------------------------------------------------------------------------
// FRAGMENT-MAJOR tile format for all 32x1024 bf16 A-tiles (h and seqb):
//   u16 offset F(row, col) = (row>>4)*16384 + (col>>5)*512
//                          + (((col>>3)&3)*16 + (row&15))*8 + (col&7)
// Linear 16B/lane copies + linear MFMA reads -> zero bank conflicts.
// ---------------------------------------------------------------------------

// Weight conversion: W{x,h}{0,1} fp32 [4096][1024] -> Wcat bf16 [4096][2048]
__global__ void cvt_weights(const float* __restrict__ Wx0, const float* __restrict__ Wh0,
                            const float* __restrict__ Wx1, const float* __restrict__ Wh1,
                            unsigned short* __restrict__ W0, unsigned short* __restrict__ W1) {
    size_t idx = ((size_t)blockIdx.x * 256 + threadIdx.x) * 8;
    const size_t LSZ = (size_t)4096 * 2048;
    int layer = idx >= LSZ;
    size_t e = idx - (layer ? LSZ : 0);
    int row = (int)(e >> 11);
    int k = (int)(e & 2047);
    const float* src = layer ? (k < 1024 ? Wx1 : Wh1) : (k < 1024 ? Wx0 : Wh0);
    const float* s = src + (size_t)row * 1024 + (k & 1023);
    float4 lo = ((const float4*)s)[0], hi = ((const float4*)s)[1];
    *reinterpret_cast<bf16x8*>((layer ? W1 : W0) + e) = cvt8(lo, hi);
}

// sequence [B][T][I] fp32 -> seqb [T][btile][fragment-major 32x1024 tile] bf16
__global__ void cvt_seq(const float* __restrict__ seq, unsigned short* __restrict__ seqb, int T) {
    int t = blockIdx.x >> 6, b = blockIdx.x & 63;
    int row = b & 31, btile = b >> 5, tid = threadIdx.x;  // 128 threads, 8 cols each
    const float* s = seq + ((size_t)b * T + t) * 1024 + tid * 8;
    float4 lo = ((const float4*)s)[0], hi = ((const float4*)s)[1];
    int off = ((row >> 4) << 14) + ((tid >> 2) << 9) + (((tid & 3) << 4) + (row & 15)) * 8;
    *reinterpret_cast<bf16x8*>(seqb + ((size_t)t * 2 + btile) * 32768 + off) = cvt8(lo, hi);
}

// ---------------------------------------------------------------------------
// LDS: two A tiles (64 KB each) + DEDICATED z-exchange (no union/alias).
// 136 KB total -> still 1 block/CU (160 KB limit).
// ---------------------------------------------------------------------------
struct Smem {
    unsigned short a[2][32768];  // 128 KB
    float z[4][32][16];          // 8 KB
};

struct StageRegs { u64 q[32]; };  // 64 VGPRs, only one live at a time

__device__ inline void stage_issue(StageRegs& r, const unsigned short* __restrict__ src) {
#pragma unroll
    for (int i = 0; i < 16; ++i) {
        const u64* s = (const u64*)(src + (size_t)((threadIdx.x + (i << 8)) << 3));
        r.q[2 * i] = ld64c(s);
        r.q[2 * i + 1] = ld64c(s + 1);
    }
}

__device__ inline void stage_issue_plain(StageRegs& r, const unsigned short* __restrict__ src) {
#pragma unroll
    for (int i = 0; i < 16; ++i) {
        const u64* s = (const u64*)(src + (size_t)((threadIdx.x + (i << 8)) << 3));
        r.q[2 * i] = s[0];
        r.q[2 * i + 1] = s[1];
    }
}

__device__ inline void stage_write(const StageRegs& r, unsigned short* tile) {
#pragma unroll
    for (int i = 0; i < 16; ++i) {
        u64* d = (u64*)(tile + (size_t)((threadIdx.x + (i << 8)) << 3));
        d[0] = r.q[2 * i];
        d[1] = r.q[2 * i + 1];
    }
}

// MFMA K=1024 pass: A linear fragment-major LDS, B from persistent registers.
template <int BASE>
__device__ inline void mfma_pass(const unsigned short* tile, const bf16x8 (&w)[64],
                                 f32x4& acc0, f32x4& acc1, int lane) {
#pragma unroll
    for (int kk = 0; kk < 32; ++kk) {
        bf16x8 av0 = *(const bf16x8*)(tile + kk * 512 + lane * 8);
        bf16x8 av1 = *(const bf16x8*)(tile + 16384 + kk * 512 + lane * 8);
        acc0 = __builtin_amdgcn_mfma_f32_16x16x32_bf16(av0, w[BASE + kk], acc0, 0, 0, 0);
        acc1 = __builtin_amdgcn_mfma_f32_16x16x32_bf16(av1, w[BASE + kk], acc1, 0, 0, 0);
    }
}

// ---------------------------------------------------------------------------
// Persistent skew-2 2-layer LSTM, full weight panel in registers.
// == round-14 base + {per-wave publish (no SYNC C), dedicated z, L0-slack} ==
// Flags: flags[bid*4 + wave] = finished_phase + 1 (per-WAVE, published right
// after that wave's vmcnt drain). Consumer thread tid polls the 16B quad of
// block tid and takes min over its 4 wave-flags.
// Spin thresholds (F = min wave-flag of polled block):
//   L0 block: F_L0 >= p, F_L1 >= p-2      (h0 has 5 slots -> 2-phase lead OK)
//   L1 block: F_L0 >= p, F_L1 >= p        (tight; keeps pre-spin s0 sound)
// WAR/RAW audit:
//   L0@p writes h0 slot p%5 (old h0[p-5]); readers L0@p-4 (F_L0>=p ok),
//     L1@p-3 (F_L1>=p-2 ok). L0 RAW h0[p-1]: F_L0>=p ok.
//   L1@p: s0=h0[p-2] staged PRE-spin, confirmed by phase p-1's spin
//     (F_L0>=p-1 => L0 finished p-2). s1=h1[p-3]: F_L1>=p ok. h1 2-slot WAR:
//     reader L1@p-1 covered by F_L1>=p.
// Barriers: SYNC 0 (join; also covers pre-spin s0 LDS write), SYNC A
// (s1 visible + a[0] reads done), SYNC B (z readable). No SYNC C.
// ---------------------------------------------------------------------------
template <bool SEQB>
__global__ __launch_bounds__(256, 1) void lstm_persistent(
    const float* __restrict__ seq, const unsigned short* __restrict__ seqb,
    const unsigned short* __restrict__ W0, const unsigned short* __restrict__ W1,
    const float* __restrict__ bias0, const float* __restrict__ bias1,
    unsigned short* h0buf, unsigned short* h1buf, unsigned int* flags,
    float* out, int T) {
    const int bid = blockIdx.x;
    const int r = bid & 7, q = bid >> 3;
    const int btile = q & 1, t2 = q >> 1;
    const int layer = t2 >> 3;
    const int jtile = ((t2 & 7) << 3) | r;
    const int j0 = jtile * 16;
    const int brow = btile * 32;

    const int tid = threadIdx.x;
    const int wave = tid >> 6, lane = tid & 63;
    const int ln15 = lane & 15, lhi = lane >> 4;

    const unsigned short* Wl = layer ? W1 : W0;
    const float* bias = layer ? bias1 : bias0;
    const unsigned short* Bbase = Wl + (size_t)(wave * 1024 + j0 + ln15) * 2048 + lhi * 8;
    unsigned short* hown = layer ? h1buf : h0buf;

    __shared__ Smem smem;

    // ---- persistent weight panel: 64 x bf16x8 = 256 VGPRs per lane ----
    bf16x8 wreg[64];
#pragma unroll
    for (int q2 = 0; q2 < 64; ++q2)
        wreg[q2] = *reinterpret_cast<const bf16x8*>(Bbase + q2 * 32);

    // epilogue mapping: thread -> (bl, jj), handles cols jj, jj+1
    const int bl = tid >> 3;
    const int jj = (tid & 7) * 2;
    const float bf0 = bias[j0 + jj],        bf1 = bias[j0 + jj + 1];
    const float bw0 = bias[1024 + j0 + jj], bw1 = bias[1024 + j0 + jj + 1];
    const float bi0 = bias[2048 + j0 + jj], bi1 = bias[2048 + j0 + jj + 1];
    const float bm0 = bias[3072 + j0 + jj], bm1 = bias[3072 + j0 + jj + 1];
    const int colg = j0 + jj;
    const int hoff = ((bl >> 4) << 14) + ((colg >> 5) << 9) +
                     ((((colg >> 3) & 3) << 4) + (bl & 15)) * 8 + (colg & 7);

    // spin target bias for the block this thread polls (block index == tid):
    // my L0: polled L0 -> p, polled L1 -> p-2.  my L1: -> p for both.
    const int tgt_bias = (layer == 0 && tid >= 128) ? 2 : 0;
    const u64* myflagq = (const u64*)&flags[tid * 4];

    float creg0 = 0.f, creg1 = 0.f;
    const int P = T + 2;

    for (int p = 0; p < P; ++p) {
        const bool act = layer ? (p >= 2) : (p < T);
        const int t = layer ? (p - 2) : p;
        const bool have0 = act && (layer == 1 || SEQB);

        // ---- stage0: issue + LDS-write BEFORE the spin (data confirmed by
        //      the PREVIOUS phase's conjunction; a[0] WAR closed pre-SYNC A) ----
        if (have0) {
            StageRegs s0;
            if (layer == 0)
                stage_issue_plain(s0, seqb + ((size_t)t * 2 + btile) * 32768);
            else
                stage_issue(s0, h0buf + (size_t)((t % 5) * 2 + btile) * 32768);
            stage_write(s0, smem.a[0]);
        }

        // ---- per-thread spin on block tid's 4 wave-flags (lagged), join ----
        {
            const int tgt = p - tgt_bias;
            if (tgt > 0) {
                for (;;) {
                    u64 a = ld64c(myflagq), b = ld64c(myflagq + 1);
                    unsigned int m0 = (unsigned int)a, m1 = (unsigned int)(a >> 32);
                    unsigned int m2 = (unsigned int)b, m3 = (unsigned int)(b >> 32);
                    unsigned int mn = min(min(m0, m1), min(m2, m3));
                    if ((int)mn >= tgt) break;
                    __builtin_amdgcn_s_sleep(1);
                }
            }
        }
        __syncthreads();  // SYNC 0: conjunction block-wide; a[0] stage visible

        if (act) {
            f32x4 acc0 = {0.f, 0.f, 0.f, 0.f};
            f32x4 acc1 = {0.f, 0.f, 0.f, 0.f};

            // ---- stage1 issue: own-layer h-prev (fresh; needs the join) ----
            StageRegs s1;
            const unsigned short* hsrc = layer
                ? h1buf + (size_t)(((t + 1) & 1) * 2 + btile) * 32768   // h1[t-1]
                : h0buf + (size_t)(((t + 4) % 5) * 2 + btile) * 32768;  // h0[t-1]
            stage_issue(s1, hsrc);

            // ---- pass 0: x-part (covers stage1 latency) ----
            if (layer == 0 && !SEQB) {
                const float* a0f = seq + ((size_t)(brow + ln15) * T + t) * 1024 + lhi * 8;
                const float* a1f = a0f + (size_t)16 * T * 1024;
#pragma unroll
                for (int kk = 0; kk < 32; ++kk) {
                    float4 l0 = ((const float4*)a0f)[0], h0v = ((const float4*)a0f)[1];
                    float4 l1 = ((const float4*)a1f)[0], h1v = ((const float4*)a1f)[1];
                    bf16x8 av0 = cvt8(l0, h0v), av1 = cvt8(l1, h1v);
                    acc0 = __builtin_amdgcn_mfma_f32_16x16x32_bf16(av0, wreg[kk], acc0, 0, 0, 0);
                    acc1 = __builtin_amdgcn_mfma_f32_16x16x32_bf16(av1, wreg[kk], acc1, 0, 0, 0);
                    a0f += 32; a1f += 32;
                }
            } else {
                mfma_pass<0>(smem.a[0], wreg, acc0, acc1, lane);
            }

            // ---- pass 1: h-part ----
            stage_write(s1, smem.a[1]);
            __syncthreads();  // SYNC A: a[1] visible; all waves done reading a[0]
            mfma_pass<32>(smem.a[1], wreg, acc0, acc1, lane);

            // ---- z-exchange (dedicated region; prev-phase readers joined) ----
#pragma unroll
            for (int rr = 0; rr < 4; ++rr) {
                smem.z[wave][4 * lhi + rr][ln15] = acc0[rr];
                smem.z[wave][16 + 4 * lhi + rr][ln15] = acc1[rr];
            }
            __syncthreads();  // SYNC B: z readable

            {
                float2 zf = *(const float2*)&smem.z[0][bl][jj];
                float2 zw = *(const float2*)&smem.z[1][bl][jj];
                float2 zi = *(const float2*)&smem.z[2][bl][jj];
                float2 zm = *(const float2*)&smem.z[3][bl][jj];
                float c0n = creg0 * sigm(zf.x + bf0) + sigm(zw.x + bw0) * tanh_f(zi.x + bi0);
                float c1n = creg1 * sigm(zf.y + bf1) + sigm(zw.y + bw1) * tanh_f(zi.y + bi1);
                float h0v = tanh_f(c0n) * sigm(zm.x + bm0);
                float h1v = tanh_f(c1n) * sigm(zm.y + bm1);
                creg0 = c0n; creg1 = c1n;
                const int wbuf = layer ? (t & 1) : (t % 5);
                unsigned short* tb = hown + (size_t)(wbuf * 2 + btile) * 32768;
                unsigned int packed = (unsigned int)f2bf(h0v) | ((unsigned int)f2bf(h1v) << 16);
                st32c((unsigned int*)(tb + hoff), packed);
                if (layer && t == T - 1) {
                    int idx = (brow + bl) * 1024 + colg;
                    out[idx] = h0v; out[idx + 1] = h1v;
                }
            }
        }

        // ---- per-WAVE publish: drain own stores (vmcnt is wave-level),
        //      then lane 0 stores this wave's flag. No block barrier. ----
        if (p < P - 1) {
            asm volatile("s_waitcnt vmcnt(0)" ::: "memory");
            if (lane == 0) st32c(&flags[bid * 4 + wave], (unsigned int)(p + 1));
        }
    }
}

// ---------------------------------------------------------------------------
extern "C" void kernel_launch(void* const* d_in, const int* in_sizes, int n_in,
                              void* d_out, int out_size, void* d_ws, size_t ws_size,
                              hipStream_t stream) {
    const float* seq = (const float*)d_in[0];
    const float* Wx0 = (const float*)d_in[1];
    const float* Wh0 = (const float*)d_in[2];
    const float* b0 = (const float*)d_in[3];
    const float* Wx1 = (const float*)d_in[4];
    const float* Wh1 = (const float*)d_in[5];
    const float* b1 = (const float*)d_in[6];
    float* out = (float*)d_out;
    char* ws = (char*)d_ws;
    const int T = 512;

    const size_t WBYTES = (size_t)4096 * 2048 * 2;         // 16.78 MB per layer
    const size_t SEQB_BYTES = (size_t)512 * 2 * 32768 * 2; // 67.1 MB (tile-major)
    const size_t H0_BYTES = 5 * 2 * 65536;                  // 5 slots x 2 btiles
    const size_t H1_BYTES = 2 * 2 * 65536;                  // 2 slots x 2 btiles
    const size_t FLAG_BYTES = 4096;                         // 1024 wave-flags
    const size_t STATE_BYTES = H0_BYTES + H1_BYTES + FLAG_BYTES;

    size_t offSeqb = 2 * WBYTES;
    bool big = ws_size >= 2 * WBYTES + SEQB_BYTES + STATE_BYTES;
    size_t offState = big ? (offSeqb + SEQB_BYTES) : offSeqb;

    unsigned short* W0p = (unsigned short*)(ws);
    unsigned short* W1p = (unsigned short*)(ws + WBYTES);
    unsigned short* seqbp = (unsigned short*)(ws + offSeqb);
    unsigned short* h0p = (unsigned short*)(ws + offState);
    unsigned short* h1p = (unsigned short*)(ws + offState + H0_BYTES);
    unsigned int* flagsp = (unsigned int*)(ws + offState + H0_BYTES + H1_BYTES);

    hipLaunchKernelGGL(cvt_weights, dim3(8192), dim3(256), 0, stream,
                       Wx0, Wh0, Wx1, Wh1, W0p, W1p);
    if (big)
        hipLaunchKernelGGL(cvt_seq, dim3(T * 64), dim3(128), 0, stream, seq, seqbp, T);
    hipMemsetAsync(ws + offState, 0, STATE_BYTES, stream);

    int Tv = T;
    void* args[] = {&seq, &seqbp, &W0p, &W1p, &b0, &b1, &h0p, &h1p, &flagsp, &out, &Tv};
    if (big) {
        hipError_t e = hipLaunchCooperativeKernel((void*)lstm_persistent<true>,
                                                  dim3(256), dim3(256), args, 0, stream);
        if (e != hipSuccess) {
            // co-residency guaranteed by capacity (1 block/CU, 256 blocks);
            // the custom flag barrier needs no cooperative-launch semantics.
            hipLaunchKernelGGL((lstm_persistent<true>), dim3(256), dim3(256), 0, stream,
                               seq, seqbp, W0p, W1p, b0, b1, h0p, h1p, flagsp, out, Tv);
        }
    } else {
        hipError_t e = hipLaunchCooperativeKernel((void*)lstm_persistent<false>,
                                                  dim3(256), dim3(256), args, 0, stream);
        if (e != hipSuccess) {
            hipLaunchKernelGGL((lstm_persistent<false>), dim3(256), dim3(256), 0, stream,
                               seq, seqbp, W0p, W1p, b0, b1, h0p, h1p, flagsp, out, Tv);
        }
    }
}

// Round 16
// 3920.553 us; speedup vs baseline: 1.1675x; 1.1675x over previous
//
#include <hip/hip_runtime.h>

typedef __bf16 bf16x8 __attribute__((ext_vector_type(8)));
typedef float f32x4 __attribute__((ext_vector_type(4)));
typedef unsigned long long u64;

__device__ inline float sigm(float x) { return 1.0f / (1.0f + __expf(-x)); }
__device__ inline float tanh_f(float x) {
    float e = __expf(2.0f * x);
    return 1.0f - 2.0f / (e + 1.0f);
}

__device__ inline unsigned short f2bf(float f) {
    __bf16 h = (__bf16)f;
    return __builtin_bit_cast(unsigned short, h);
}

__device__ inline bf16x8 cvt8(float4 lo, float4 hi) {
    bf16x8 r;
    r[0] = (__bf16)lo.x; r[1] = (__bf16)lo.y; r[2] = (__bf16)lo.z; r[3] = (__bf16)lo.w;
    r[4] = (__bf16)hi.x; r[5] = (__bf16)hi.y; r[6] = (__bf16)hi.z; r[7] = (__bf16)hi.w;
    return r;
}

// compiler-visible LLC-coherent ops (sc0 sc1, no fences, counted vmcnt)
__device__ inline u64 ld64c(const u64* p) {
    return __hip_atomic_load(p, __ATOMIC_RELAXED, __HIP_MEMORY_SCOPE_AGENT);
}
__device__ inline void st32c(unsigned int* p, unsigned int v) {
    __hip_atomic_store(p, v, __ATOMIC_RELAXED, __HIP_MEMORY_SCOPE_AGENT);
}
__device__ inline unsigned int ld32c(const unsigned int* p) {
    return __hip_atomic_load(p, __ATOMIC_RELAXED, __HIP_MEMORY_SCOPE_AGENT);
}

// ---------------------------------------------------------------------------
// FRAGMENT-MAJOR tile format for all 32x1024 bf16 A-tiles (h and seqb):
//   u16 offset F(row, col) = (row>>4)*16384 + (col>>5)*512
//                          + (((col>>3)&3)*16 + (row&15))*8 + (col&7)
// Linear 16B/lane copies + linear MFMA reads -> zero bank conflicts.
// ---------------------------------------------------------------------------

// Weight conversion: W{x,h}{0,1} fp32 [4096][1024] -> Wcat bf16 [4096][2048]
__global__ void cvt_weights(const float* __restrict__ Wx0, const float* __restrict__ Wh0,
                            const float* __restrict__ Wx1, const float* __restrict__ Wh1,
                            unsigned short* __restrict__ W0, unsigned short* __restrict__ W1) {
    size_t idx = ((size_t)blockIdx.x * 256 + threadIdx.x) * 8;
    const size_t LSZ = (size_t)4096 * 2048;
    int layer = idx >= LSZ;
    size_t e = idx - (layer ? LSZ : 0);
    int row = (int)(e >> 11);
    int k = (int)(e & 2047);
    const float* src = layer ? (k < 1024 ? Wx1 : Wh1) : (k < 1024 ? Wx0 : Wh0);
    const float* s = src + (size_t)row * 1024 + (k & 1023);
    float4 lo = ((const float4*)s)[0], hi = ((const float4*)s)[1];
    *reinterpret_cast<bf16x8*>((layer ? W1 : W0) + e) = cvt8(lo, hi);
}

// sequence [B][T][I] fp32 -> seqb [T][btile][fragment-major 32x1024 tile] bf16
__global__ void cvt_seq(const float* __restrict__ seq, unsigned short* __restrict__ seqb, int T) {
    int t = blockIdx.x >> 6, b = blockIdx.x & 63;
    int row = b & 31, btile = b >> 5, tid = threadIdx.x;  // 128 threads, 8 cols each
    const float* s = seq + ((size_t)b * T + t) * 1024 + tid * 8;
    float4 lo = ((const float4*)s)[0], hi = ((const float4*)s)[1];
    int off = ((row >> 4) << 14) + ((tid >> 2) << 9) + (((tid & 3) << 4) + (row & 15)) * 8;
    *reinterpret_cast<bf16x8*>(seqb + ((size_t)t * 2 + btile) * 32768 + off) = cvt8(lo, hi);
}

// ---------------------------------------------------------------------------
// LDS: two A tiles (64 KB each, fragment-major, linear);
// z-exchange aliases tile a[0] (separated by syncs as annotated below).
// ---------------------------------------------------------------------------
union SmemU {
    unsigned short a[2][32768];  // 128 KB
    float z[4][32][16];          // 8 KB (aliases a[0])
};

struct StageRegs { u64 q[32]; };  // 64 VGPRs, only one live at a time

__device__ inline void stage_issue(StageRegs& r, const unsigned short* __restrict__ src) {
#pragma unroll
    for (int i = 0; i < 16; ++i) {
        const u64* s = (const u64*)(src + (size_t)((threadIdx.x + (i << 8)) << 3));
        r.q[2 * i] = ld64c(s);
        r.q[2 * i + 1] = ld64c(s + 1);
    }
}

__device__ inline void stage_issue_plain(StageRegs& r, const unsigned short* __restrict__ src) {
#pragma unroll
    for (int i = 0; i < 16; ++i) {
        const u64* s = (const u64*)(src + (size_t)((threadIdx.x + (i << 8)) << 3));
        r.q[2 * i] = s[0];
        r.q[2 * i + 1] = s[1];
    }
}

__device__ inline void stage_write(const StageRegs& r, unsigned short* tile) {
#pragma unroll
    for (int i = 0; i < 16; ++i) {
        u64* d = (u64*)(tile + (size_t)((threadIdx.x + (i << 8)) << 3));
        d[0] = r.q[2 * i];
        d[1] = r.q[2 * i + 1];
    }
}

// MFMA K=1024 pass: A linear fragment-major LDS, B from persistent registers.
template <int BASE>
__device__ inline void mfma_pass(const unsigned short* tile, const bf16x8 (&w)[64],
                                 f32x4& acc0, f32x4& acc1, int lane) {
#pragma unroll
    for (int kk = 0; kk < 32; ++kk) {
        bf16x8 av0 = *(const bf16x8*)(tile + kk * 512 + lane * 8);
        bf16x8 av1 = *(const bf16x8*)(tile + 16384 + kk * 512 + lane * 8);
        acc0 = __builtin_amdgcn_mfma_f32_16x16x32_bf16(av0, w[BASE + kk], acc0, 0, 0, 0);
        acc1 = __builtin_amdgcn_mfma_f32_16x16x32_bf16(av1, w[BASE + kk], acc1, 0, 0, 0);
    }
}

// ---------------------------------------------------------------------------
// Persistent skew-2 pipelined 2-layer LSTM, FULL weight panel in registers
// (wreg[64] = 256 VGPR/lane): zero weight traffic per phase.
// == round-14 structure (best sound kernel of the session) ==
// Phase:
//   issue s0 + write s0 into a[0]   (x-tile; DATA confirmed by the PREVIOUS
//       phase's conjunction; LDS WAR vs prev epilogue closed by prev SYNC C)
//   per-thread spin flags[tid] >= p -> SYNC 0 (conjunction, block-wide)
//   issue s1 (fresh h, post-join) -> pass0 over a[0] (covers s1's RT)
//   write s1 into a[1] -> SYNC A (also proves all waves done with a[0])
//   pass1 over a[1] -> z-write (aliases a[0], safe) -> SYNC B
//   epilogue (c,h update; packed 4B h-store) -> SYNC C (vmcnt drain) ->
//   publish flags[bid] = p+1.
// Soundness of s0-before-join: L1's s0 = h0[p-2], published with flag p-1,
// confirmed by the spin at phase p-1. WAR: slot (p-2)%3 is next overwritten
// by L0 at phase p+1, which requires flags >= p+1, i.e. after this block
// finished phase p. L0's s0 = seqb (immutable).
// ---------------------------------------------------------------------------
template <bool SEQB>
__global__ __launch_bounds__(256, 1) void lstm_persistent(
    const float* __restrict__ seq, const unsigned short* __restrict__ seqb,
    const unsigned short* __restrict__ W0, const unsigned short* __restrict__ W1,
    const float* __restrict__ bias0, const float* __restrict__ bias1,
    unsigned short* h0buf, unsigned short* h1buf, unsigned int* flags,
    float* out, int T) {
    const int bid = blockIdx.x;
    const int r = bid & 7, q = bid >> 3;
    const int btile = q & 1, t2 = q >> 1;
    const int layer = t2 >> 3;
    const int jtile = ((t2 & 7) << 3) | r;
    const int j0 = jtile * 16;
    const int brow = btile * 32;

    const int tid = threadIdx.x;
    const int wave = tid >> 6, lane = tid & 63;
    const int ln15 = lane & 15, lhi = lane >> 4;

    const unsigned short* Wl = layer ? W1 : W0;
    const float* bias = layer ? bias1 : bias0;
    const unsigned short* Bbase = Wl + (size_t)(wave * 1024 + j0 + ln15) * 2048 + lhi * 8;
    unsigned short* hown = layer ? h1buf : h0buf;

    __shared__ SmemU smem;

    // ---- persistent weight panel: 64 x bf16x8 = 256 VGPRs per lane ----
    bf16x8 wreg[64];
#pragma unroll
    for (int q2 = 0; q2 < 64; ++q2)
        wreg[q2] = *reinterpret_cast<const bf16x8*>(Bbase + q2 * 32);

    // epilogue mapping: thread -> (bl, jj), handles cols jj, jj+1
    const int bl = tid >> 3;
    const int jj = (tid & 7) * 2;
    const float bf0 = bias[j0 + jj],        bf1 = bias[j0 + jj + 1];
    const float bw0 = bias[1024 + j0 + jj], bw1 = bias[1024 + j0 + jj + 1];
    const float bi0 = bias[2048 + j0 + jj], bi1 = bias[2048 + j0 + jj + 1];
    const float bm0 = bias[3072 + j0 + jj], bm1 = bias[3072 + j0 + jj + 1];
    // fragment-major u16 offset within the destination h-tile
    const int colg = j0 + jj;
    const int hoff = ((bl >> 4) << 14) + ((colg >> 5) << 9) +
                     ((((colg >> 3) & 3) << 4) + (bl & 15)) * 8 + (colg & 7);

    float creg0 = 0.f, creg1 = 0.f;
    const int P = T + 2;

    for (int p = 0; p < P; ++p) {
        const bool act = layer ? (p >= 2) : (p < T);
        const int t = layer ? (p - 2) : p;
        const bool have0 = act && (layer == 1 || SEQB);

        // ---- stage0: issue + LDS-write BEFORE the spin (off critical path) ----
        if (have0) {
            StageRegs s0;
            if (layer == 0)
                stage_issue_plain(s0, seqb + ((size_t)t * 2 + btile) * 32768);
            else
                stage_issue(s0, h0buf + (size_t)((t % 3) * 2 + btile) * 32768);
            stage_write(s0, smem.a[0]);
        }

        // ---- per-thread spin, then ONE join barrier (conjunction) ----
        if (p > 0) {
            const unsigned int tgt = (unsigned int)p;
            unsigned int pv = ld32c(&flags[tid]);
            while (pv < tgt) { __builtin_amdgcn_s_sleep(1); pv = ld32c(&flags[tid]); }
        }
        __syncthreads();  // SYNC 0: all 256 flags >= p confirmed block-wide; a[0] visible

        if (act) {
            f32x4 acc0 = {0.f, 0.f, 0.f, 0.f};
            f32x4 acc1 = {0.f, 0.f, 0.f, 0.f};

            // ---- stage1 issue: own-layer h-prev (fresh; needs the join) ----
            StageRegs s1;
            const unsigned short* hsrc = layer
                ? h1buf + (size_t)(((t + 1) & 1) * 2 + btile) * 32768   // h1[t-1]
                : h0buf + (size_t)(((t + 2) % 3) * 2 + btile) * 32768;  // h0[t-1]
            stage_issue(s1, hsrc);

            // ---- pass 0: x-part (covers stage1 latency) ----
            if (layer == 0 && !SEQB) {
                const float* a0f = seq + ((size_t)(brow + ln15) * T + t) * 1024 + lhi * 8;
                const float* a1f = a0f + (size_t)16 * T * 1024;
#pragma unroll
                for (int kk = 0; kk < 32; ++kk) {
                    float4 l0 = ((const float4*)a0f)[0], h0v = ((const float4*)a0f)[1];
                    float4 l1 = ((const float4*)a1f)[0], h1v = ((const float4*)a1f)[1];
                    bf16x8 av0 = cvt8(l0, h0v), av1 = cvt8(l1, h1v);
                    acc0 = __builtin_amdgcn_mfma_f32_16x16x32_bf16(av0, wreg[kk], acc0, 0, 0, 0);
                    acc1 = __builtin_amdgcn_mfma_f32_16x16x32_bf16(av1, wreg[kk], acc1, 0, 0, 0);
                    a0f += 32; a1f += 32;
                }
            } else {
                mfma_pass<0>(smem.a[0], wreg, acc0, acc1, lane);
            }

            // ---- pass 1: h-part ----
            stage_write(s1, smem.a[1]);
            __syncthreads();  // SYNC A: a[1] visible; all waves done reading a[0]
            mfma_pass<32>(smem.a[1], wreg, acc0, acc1, lane);

            // ---- z-exchange (z aliases a[0]; a[0] reads completed pre-SYNC A) ----
#pragma unroll
            for (int rr = 0; rr < 4; ++rr) {
                smem.z[wave][4 * lhi + rr][ln15] = acc0[rr];
                smem.z[wave][16 + 4 * lhi + rr][ln15] = acc1[rr];
            }
            __syncthreads();  // SYNC B: z readable

            {
                float2 zf = *(const float2*)&smem.z[0][bl][jj];
                float2 zw = *(const float2*)&smem.z[1][bl][jj];
                float2 zi = *(const float2*)&smem.z[2][bl][jj];
                float2 zm = *(const float2*)&smem.z[3][bl][jj];
                float c0n = creg0 * sigm(zf.x + bf0) + sigm(zw.x + bw0) * tanh_f(zi.x + bi0);
                float c1n = creg1 * sigm(zf.y + bf1) + sigm(zw.y + bw1) * tanh_f(zi.y + bi1);
                float h0v = tanh_f(c0n) * sigm(zm.x + bm0);
                float h1v = tanh_f(c1n) * sigm(zm.y + bm1);
                creg0 = c0n; creg1 = c1n;
                const int wbuf = layer ? (t & 1) : (t % 3);
                unsigned short* tb = hown + (size_t)(wbuf * 2 + btile) * 32768;
                unsigned int packed = (unsigned int)f2bf(h0v) | ((unsigned int)f2bf(h1v) << 16);
                st32c((unsigned int*)(tb + hoff), packed);
                if (layer && t == T - 1) {
                    int idx = (brow + bl) * 1024 + colg;
                    out[idx] = h0v; out[idx + 1] = h1v;
                }
            }
        }

        // ---- publish phase completion ----
        if (p < P - 1) {
            __syncthreads();  // SYNC C: drains vmcnt (h-stores LLC-visible); WAR fence a/z
            if (tid == 0) st32c(&flags[bid], (unsigned int)(p + 1));
        }
    }
}

// ---------------------------------------------------------------------------
extern "C" void kernel_launch(void* const* d_in, const int* in_sizes, int n_in,
                              void* d_out, int out_size, void* d_ws, size_t ws_size,
                              hipStream_t stream) {
    const float* seq = (const float*)d_in[0];
    const float* Wx0 = (const float*)d_in[1];
    const float* Wh0 = (const float*)d_in[2];
    const float* b0 = (const float*)d_in[3];
    const float* Wx1 = (const float*)d_in[4];
    const float* Wh1 = (const float*)d_in[5];
    const float* b1 = (const float*)d_in[6];
    float* out = (float*)d_out;
    char* ws = (char*)d_ws;
    const int T = 512;

    const size_t WBYTES = (size_t)4096 * 2048 * 2;         // 16.78 MB per layer
    const size_t SEQB_BYTES = (size_t)512 * 2 * 32768 * 2; // 67.1 MB (tile-major)
    const size_t H0_BYTES = 3 * 2 * 65536;                  // 3 slots x 2 btiles
    const size_t H1_BYTES = 2 * 2 * 65536;                  // 2 slots x 2 btiles
    const size_t STATE_BYTES = H0_BYTES + H1_BYTES + 1024;  // + flags

    size_t offSeqb = 2 * WBYTES;
    bool big = ws_size >= 2 * WBYTES + SEQB_BYTES + STATE_BYTES;
    size_t offState = big ? (offSeqb + SEQB_BYTES) : offSeqb;

    unsigned short* W0p = (unsigned short*)(ws);
    unsigned short* W1p = (unsigned short*)(ws + WBYTES);
    unsigned short* seqbp = (unsigned short*)(ws + offSeqb);
    unsigned short* h0p = (unsigned short*)(ws + offState);
    unsigned short* h1p = (unsigned short*)(ws + offState + H0_BYTES);
    unsigned int* flagsp = (unsigned int*)(ws + offState + H0_BYTES + H1_BYTES);

    hipLaunchKernelGGL(cvt_weights, dim3(8192), dim3(256), 0, stream,
                       Wx0, Wh0, Wx1, Wh1, W0p, W1p);
    if (big)
        hipLaunchKernelGGL(cvt_seq, dim3(T * 64), dim3(128), 0, stream, seq, seqbp, T);
    hipMemsetAsync(ws + offState, 0, STATE_BYTES, stream);

    int Tv = T;
    void* args[] = {&seq, &seqbp, &W0p, &W1p, &b0, &b1, &h0p, &h1p, &flagsp, &out, &Tv};
    if (big) {
        hipError_t e = hipLaunchCooperativeKernel((void*)lstm_persistent<true>,
                                                  dim3(256), dim3(256), args, 0, stream);
        if (e != hipSuccess) {
            // co-residency guaranteed by capacity (1 block/CU, 256 blocks);
            // the custom flag barrier needs no cooperative-launch semantics.
            hipLaunchKernelGGL((lstm_persistent<true>), dim3(256), dim3(256), 0, stream,
                               seq, seqbp, W0p, W1p, b0, b1, h0p, h1p, flagsp, out, Tv);
        }
    } else {
        hipError_t e = hipLaunchCooperativeKernel((void*)lstm_persistent<false>,
                                                  dim3(256), dim3(256), args, 0, stream);
        if (e != hipSuccess) {
            hipLaunchKernelGGL((lstm_persistent<false>), dim3(256), dim3(256), 0, stream,
                               seq, seqbp, W0p, W1p, b0, b1, h0p, h1p, flagsp, out, Tv);
        }
    }
}